// Round 1
// baseline (1039.957 us; speedup 1.0000x reference)
//
#include <hip/hip_runtime.h>

#define DIM   384
#define HEADS 12
#define NTOK  49
#define NWIN  2048
#define NMASK 64
#define HD    32
#define MTOT  (NWIN * NTOK)   // 100352

typedef __bf16 bf16x8 __attribute__((ext_vector_type(8)));
typedef float  floatx4 __attribute__((ext_vector_type(4)));

__device__ __forceinline__ unsigned short f2bf(float f) {
  unsigned int u = __builtin_bit_cast(unsigned int, f);
  u += 0x7fffu + ((u >> 16) & 1u);   // RNE
  return (unsigned short)(u >> 16);
}
__device__ __forceinline__ float bf2f(unsigned short s) {
  unsigned int u = ((unsigned int)s) << 16;
  return __builtin_bit_cast(float, u);
}
__device__ __forceinline__ void async_copy16(const void* g, void* l) {
  __builtin_amdgcn_global_load_lds((const __attribute__((address_space(1))) void*)g,
                                   (__attribute__((address_space(3))) void*)l, 16, 0, 0);
}

// ---------------------------------------------------------------------------
// prep: fp32 -> bf16 converts + per-head relative-position bias table
// ---------------------------------------------------------------------------
__global__ void prep_kernel(const float* __restrict__ x,
                            const float* __restrict__ qkv_w,
                            const float* __restrict__ proj_w,
                            const float* __restrict__ rel_table,
                            const int*   __restrict__ rel_index,
                            unsigned short* __restrict__ xb,
                            unsigned short* __restrict__ qkv_wb,
                            unsigned short* __restrict__ proj_wb,
                            float* __restrict__ biasT) {
  const int tid  = blockIdx.x * blockDim.x + threadIdx.x;
  const int nthr = gridDim.x * blockDim.x;

  const int nx4 = (MTOT * DIM) / 4;               // 9,633,792
  for (int i = tid; i < nx4; i += nthr) {
    float4 v = ((const float4*)x)[i];
    ushort4 o = { f2bf(v.x), f2bf(v.y), f2bf(v.z), f2bf(v.w) };
    ((ushort4*)xb)[i] = o;
  }
  const int nw4 = (3 * DIM * DIM) / 4;            // 110,592
  for (int i = tid; i < nw4; i += nthr) {
    float4 v = ((const float4*)qkv_w)[i];
    ushort4 o = { f2bf(v.x), f2bf(v.y), f2bf(v.z), f2bf(v.w) };
    ((ushort4*)qkv_wb)[i] = o;
  }
  const int np4 = (DIM * DIM) / 4;                // 36,864
  for (int i = tid; i < np4; i += nthr) {
    float4 v = ((const float4*)proj_w)[i];
    ushort4 o = { f2bf(v.x), f2bf(v.y), f2bf(v.z), f2bf(v.w) };
    ((ushort4*)proj_wb)[i] = o;
  }
  const int nb = HEADS * NTOK * NTOK;             // 28,812
  for (int i = tid; i < nb; i += nthr) {
    int h = i / (NTOK * NTOK);
    int ij = i - h * (NTOK * NTOK);
    biasT[i] = rel_table[rel_index[ij] * HEADS + h];
  }
}

// ---------------------------------------------------------------------------
// gemm_bt: C[M,N] = A[M,K] * W[N,K]^T + bias[N]; A,W bf16, acc fp32.
// m97 structure: 128x128 tile, BK=32, 256 thr (4 waves, 2x2), 4x4 MFMAs/wave,
// global_load_lds width-16 staging (LDS layout = lane-contiguous, no padding).
// ---------------------------------------------------------------------------
template <int OUT_BF16>
__global__ __launch_bounds__(256, 2)
void gemm_bt(const unsigned short* __restrict__ A,
             const unsigned short* __restrict__ W,
             const float* __restrict__ bias,
             void* __restrict__ Cout,
             int M, int N, int K) {
  __shared__ __align__(16) char lds[16384];   // A: [0,8192), B: [8192,16384)
  char* ldsA = lds;
  char* ldsB = lds + 8192;

  const int tid  = threadIdx.x;
  const int lane = tid & 63;
  const int wave = tid >> 6;
  const int wr   = wave >> 1;       // wave row (0..1) -> 64 rows of C
  const int wc   = wave & 1;        // wave col (0..1) -> 64 cols of C
  const int q4   = lane >> 4;       // quad 0..3
  const int lm   = lane & 15;

  const int tileM = blockIdx.y * 128;
  const int tileN = blockIdx.x * 128;

  // staging: thread t loads 16B (8 bf16 along K) for row t>>2, col8 (t&3)*8;
  // two rounds of 64 rows each, for both A and B.
  const int srow = tid >> 2;
  const int scol = (tid & 3) * 8;
  const unsigned short* gA = A + (size_t)(tileM + srow) * K + scol;
  const unsigned short* gB = W + (size_t)(tileN + srow) * K + scol;
  const int loff = tid * 16;        // row*64B + col8*2B == tid*16

  // fragment LDS offsets (row stride 64B, quad picks 16B k-chunk)
  const int aoff = (wr * 64 + lm) * 64 + q4 * 16;
  const int boff = (wc * 64 + lm) * 64 + q4 * 16;

  floatx4 acc[4][4] = {};

  for (int k0 = 0; k0 < K; k0 += 32) {
    async_copy16(gA,            ldsA + loff);
    async_copy16(gA + 64 * K,   ldsA + 4096 + loff);
    async_copy16(gB,            ldsB + loff);
    async_copy16(gB + 64 * K,   ldsB + 4096 + loff);
    gA += 32; gB += 32;
    __syncthreads();               // drains vmcnt -> LDS writes visible

    bf16x8 af[4], bfr[4];
#pragma unroll
    for (int i = 0; i < 4; i++) {
      af[i]  = *(const bf16x8*)(ldsA + aoff + i * 1024);
      bfr[i] = *(const bf16x8*)(ldsB + boff + i * 1024);
    }
#pragma unroll
    for (int i = 0; i < 4; i++)
#pragma unroll
      for (int j = 0; j < 4; j++)
        acc[i][j] = __builtin_amdgcn_mfma_f32_16x16x32_bf16(af[i], bfr[j], acc[i][j], 0, 0, 0);
    __syncthreads();               // protect LDS before next stage
  }

  // epilogue: C[row][col], col = lane&15 (+j*16), row = quad*4+reg (+i*16)
  const int browb = tileM + wr * 64 + q4 * 4;
  const int bcolb = tileN + wc * 64 + lm;
#pragma unroll
  for (int j = 0; j < 4; j++) {
    const int col = bcolb + j * 16;
    const float bv = bias[col];
#pragma unroll
    for (int i = 0; i < 4; i++) {
#pragma unroll
      for (int r = 0; r < 4; r++) {
        const int row = browb + i * 16 + r;
        const float v = acc[i][j][r] + bv;
        if (OUT_BF16)
          ((unsigned short*)Cout)[(size_t)row * N + col] = f2bf(v);
        else
          ((float*)Cout)[(size_t)row * N + col] = v;
      }
    }
  }
}

// ---------------------------------------------------------------------------
// attn: one wave per (window b, head h). K/V fp32 in LDS (broadcast reads),
// q in regs (scale folded), row softmax, bf16 out in [b,i,h,hd] layout.
// ---------------------------------------------------------------------------
__global__ __launch_bounds__(64)
void attn_kernel(const unsigned short* __restrict__ qkv,
                 const float* __restrict__ mask,
                 const float* __restrict__ biasT,
                 unsigned short* __restrict__ attn_out) {
  __shared__ float kvs[2][NTOK][HD];   // k, v
  __shared__ float qf[NTOK][HD + 1];   // +1 pad: per-lane row reads conflict-free
  __shared__ float S[NTOK][51];        // stride 51 (odd) -> <=2-way conflicts

  const int b = blockIdx.x;
  const int h = blockIdx.y;
  const int lane = threadIdx.x;

  const unsigned short* base = qkv + (size_t)b * NTOK * (3 * DIM) + h * HD;
  for (int idx = lane; idx < NTOK * (HD / 2); idx += 64) {
    const int r = idx >> 4;
    const int c = (idx & 15) * 2;
    const unsigned short* rp = base + (size_t)r * (3 * DIM);
    unsigned int uq = *(const unsigned int*)(rp + c);
    unsigned int uk = *(const unsigned int*)(rp + DIM + c);
    unsigned int uv = *(const unsigned int*)(rp + 2 * DIM + c);
    qf[r][c]     = bf2f((unsigned short)uq);
    qf[r][c + 1] = bf2f((unsigned short)(uq >> 16));
    kvs[0][r][c]     = bf2f((unsigned short)uk);
    kvs[0][r][c + 1] = bf2f((unsigned short)(uk >> 16));
    kvs[1][r][c]     = bf2f((unsigned short)uv);
    kvs[1][r][c + 1] = bf2f((unsigned short)(uv >> 16));
  }
  __syncthreads();

  if (lane < NTOK) {
    const float scale = 0.17677669529663687f;   // 32^-0.5
    float q[HD];
#pragma unroll
    for (int d = 0; d < HD; d++) q[d] = qf[lane][d] * scale;

    const float* mrow = mask  + (size_t)(b & (NMASK - 1)) * (NTOK * NTOK) + lane * NTOK;
    const float* brow = biasT + (size_t)h * (NTOK * NTOK) + lane * NTOK;

    float m = -1e30f;
    for (int j = 0; j < NTOK; j++) {
      float s0 = 0.f, s1 = 0.f, s2 = 0.f, s3 = 0.f;
      const float4* kj = (const float4*)kvs[0][j];
#pragma unroll
      for (int dd = 0; dd < 8; dd++) {
        float4 kk = kj[dd];
        s0 = fmaf(q[4 * dd],     kk.x, s0);
        s1 = fmaf(q[4 * dd + 1], kk.y, s1);
        s2 = fmaf(q[4 * dd + 2], kk.z, s2);
        s3 = fmaf(q[4 * dd + 3], kk.w, s3);
      }
      float s = (s0 + s1) + (s2 + s3) + brow[j] + mrow[j];
      m = fmaxf(m, s);
      S[lane][j] = s;
    }

    float l = 0.f;
    for (int j = 0; j < NTOK; j++) {
      float p = __expf(S[lane][j] - m);
      l += p;
      S[lane][j] = p;
    }

    float O[HD];
#pragma unroll
    for (int d = 0; d < HD; d++) O[d] = 0.f;
    for (int j = 0; j < NTOK; j++) {
      float p = S[lane][j];
      const float4* vj = (const float4*)kvs[1][j];
#pragma unroll
      for (int dd = 0; dd < 8; dd++) {
        float4 vv = vj[dd];
        O[4 * dd]     = fmaf(p, vv.x, O[4 * dd]);
        O[4 * dd + 1] = fmaf(p, vv.y, O[4 * dd + 1]);
        O[4 * dd + 2] = fmaf(p, vv.z, O[4 * dd + 2]);
        O[4 * dd + 3] = fmaf(p, vv.w, O[4 * dd + 3]);
      }
    }

    const float inv = 1.0f / l;
    unsigned short* orow = attn_out + ((size_t)b * NTOK + lane) * DIM + h * HD;
#pragma unroll
    for (int d = 0; d < HD; d += 2) {
      unsigned int pk = (unsigned int)f2bf(O[d] * inv) |
                        ((unsigned int)f2bf(O[d + 1] * inv) << 16);
      *(unsigned int*)(orow + d) = pk;
    }
  }
}

// ---------------------------------------------------------------------------
// launch
// ---------------------------------------------------------------------------
extern "C" void kernel_launch(void* const* d_in, const int* in_sizes, int n_in,
                              void* d_out, int out_size, void* d_ws, size_t ws_size,
                              hipStream_t stream) {
  const float* x         = (const float*)d_in[0];
  const float* mask      = (const float*)d_in[1];
  const float* qkv_w     = (const float*)d_in[2];
  const float* qkv_b     = (const float*)d_in[3];
  const float* proj_w    = (const float*)d_in[4];
  const float* proj_b    = (const float*)d_in[5];
  const float* rel_table = (const float*)d_in[6];
  const int*   rel_index = (const int*)d_in[7];
  float* out = (float*)d_out;

  char* ws = (char*)d_ws;
  // xb (and later attn_out, aliased): 100352*384*2 = 77,070,336 B
  unsigned short* xb      = (unsigned short*)(ws);
  unsigned short* qkvbuf  = (unsigned short*)(ws + 77070336);    // 100352*1152*2
  unsigned short* qkv_wb  = (unsigned short*)(ws + 308281344);   // 1152*384*2
  unsigned short* proj_wb = (unsigned short*)(ws + 309166080);   // 384*384*2
  float*          biasT   = (float*)(ws + 309460992);            // 12*2401*4

  prep_kernel<<<2048, 256, 0, stream>>>(x, qkv_w, proj_w, rel_table, rel_index,
                                        xb, qkv_wb, proj_wb, biasT);

  gemm_bt<1><<<dim3((3 * DIM) / 128, MTOT / 128), 256, 0, stream>>>(
      xb, qkv_wb, qkv_b, qkvbuf, MTOT, 3 * DIM, DIM);

  attn_kernel<<<dim3(NWIN, HEADS), 64, 0, stream>>>(qkvbuf, mask, biasT, xb /*attn_out*/);

  gemm_bt<0><<<dim3(DIM / 128, MTOT / 128), 256, 0, stream>>>(
      xb /*attn_out*/, proj_wb, proj_b, out, MTOT, DIM, DIM);
}

// Round 2
// 664.258 us; speedup vs baseline: 1.5656x; 1.5656x over previous
//
#include <hip/hip_runtime.h>

#define DIM   384
#define HEADS 12
#define NTOK  49
#define NWIN  2048
#define NMASK 64
#define HD    32
#define MTOT  (NWIN * NTOK)   // 100352

typedef __bf16 bf16x8 __attribute__((ext_vector_type(8)));
typedef float  floatx4 __attribute__((ext_vector_type(4)));

__device__ __forceinline__ unsigned short f2bf(float f) {
  unsigned int u = __builtin_bit_cast(unsigned int, f);
  u += 0x7fffu + ((u >> 16) & 1u);   // RNE
  return (unsigned short)(u >> 16);
}
__device__ __forceinline__ void async_copy16(const void* g, void* l) {
  __builtin_amdgcn_global_load_lds((const __attribute__((address_space(1))) void*)g,
                                   (__attribute__((address_space(3))) void*)l, 16, 0, 0);
}

// ---------------------------------------------------------------------------
// prep: fp32 -> bf16 converts + lane-swizzled padded bias table
// biasP[h][tile t][lane][reg] : r = (t>>2)*16 + (lane>>4)*4 + reg,
//                               c = (t&3)*16 + (lane&15); pad(-1e30) if r/c>=49
// ---------------------------------------------------------------------------
__global__ void prep_kernel(const float* __restrict__ x,
                            const float* __restrict__ qkv_w,
                            const float* __restrict__ proj_w,
                            const float* __restrict__ rel_table,
                            const int*   __restrict__ rel_index,
                            unsigned short* __restrict__ xb,
                            unsigned short* __restrict__ qkv_wb,
                            unsigned short* __restrict__ proj_wb,
                            float* __restrict__ biasP) {
  const int tid  = blockIdx.x * blockDim.x + threadIdx.x;
  const int nthr = gridDim.x * blockDim.x;

  const int nx4 = (MTOT * DIM) / 4;
  for (int i = tid; i < nx4; i += nthr) {
    float4 v = ((const float4*)x)[i];
    ushort4 o = { f2bf(v.x), f2bf(v.y), f2bf(v.z), f2bf(v.w) };
    ((ushort4*)xb)[i] = o;
  }
  const int nw4 = (3 * DIM * DIM) / 4;
  for (int i = tid; i < nw4; i += nthr) {
    float4 v = ((const float4*)qkv_w)[i];
    ushort4 o = { f2bf(v.x), f2bf(v.y), f2bf(v.z), f2bf(v.w) };
    ((ushort4*)qkv_wb)[i] = o;
  }
  const int np4 = (DIM * DIM) / 4;
  for (int i = tid; i < np4; i += nthr) {
    float4 v = ((const float4*)proj_w)[i];
    ushort4 o = { f2bf(v.x), f2bf(v.y), f2bf(v.z), f2bf(v.w) };
    ((ushort4*)proj_wb)[i] = o;
  }
  // biasP: 12 heads * 16 tiles * 64 lanes float4s = 12288 float4
  for (int i = tid; i < 12288; i += nthr) {
    const int lane = i & 63;
    const int t    = (i >> 6) & 15;
    const int h    = i >> 10;
    const int rb   = (t >> 2) * 16 + (lane >> 4) * 4;
    const int c    = (t & 3) * 16 + (lane & 15);
    float4 o;
    float* op = (float*)&o;
#pragma unroll
    for (int reg = 0; reg < 4; reg++) {
      const int r = rb + reg;
      op[reg] = (r < NTOK && c < NTOK)
                  ? rel_table[rel_index[r * NTOK + c] * HEADS + h]
                  : -1e30f;
    }
    ((float4*)biasP)[i] = o;
  }
}

// ---------------------------------------------------------------------------
// gemm_bt: C[M,N] = A[M,K] * W[N,K]^T + bias[N]; bf16 in, fp32 acc
// ---------------------------------------------------------------------------
template <int OUT_BF16>
__global__ __launch_bounds__(256, 2)
void gemm_bt(const unsigned short* __restrict__ A,
             const unsigned short* __restrict__ W,
             const float* __restrict__ bias,
             void* __restrict__ Cout,
             int M, int N, int K) {
  __shared__ __align__(16) char lds[16384];
  char* ldsA = lds;
  char* ldsB = lds + 8192;

  const int tid  = threadIdx.x;
  const int lane = tid & 63;
  const int wave = tid >> 6;
  const int wr   = wave >> 1;
  const int wc   = wave & 1;
  const int q4   = lane >> 4;
  const int lm   = lane & 15;

  const int tileM = blockIdx.y * 128;
  const int tileN = blockIdx.x * 128;

  const int srow = tid >> 2;
  const int scol = (tid & 3) * 8;
  const unsigned short* gA = A + (size_t)(tileM + srow) * K + scol;
  const unsigned short* gB = W + (size_t)(tileN + srow) * K + scol;
  const int loff = tid * 16;

  const int aoff = (wr * 64 + lm) * 64 + q4 * 16;
  const int boff = (wc * 64 + lm) * 64 + q4 * 16;

  floatx4 acc[4][4] = {};

  for (int k0 = 0; k0 < K; k0 += 32) {
    async_copy16(gA,          ldsA + loff);
    async_copy16(gA + 64 * K, ldsA + 4096 + loff);
    async_copy16(gB,          ldsB + loff);
    async_copy16(gB + 64 * K, ldsB + 4096 + loff);
    gA += 32; gB += 32;
    __syncthreads();

    bf16x8 af[4], bfr[4];
#pragma unroll
    for (int i = 0; i < 4; i++) {
      af[i]  = *(const bf16x8*)(ldsA + aoff + i * 1024);
      bfr[i] = *(const bf16x8*)(ldsB + boff + i * 1024);
    }
#pragma unroll
    for (int i = 0; i < 4; i++)
#pragma unroll
      for (int j = 0; j < 4; j++)
        acc[i][j] = __builtin_amdgcn_mfma_f32_16x16x32_bf16(af[i], bfr[j], acc[i][j], 0, 0, 0);
    __syncthreads();
  }

  const int browb = tileM + wr * 64 + q4 * 4;
  const int bcolb = tileN + wc * 64 + lm;
#pragma unroll
  for (int j = 0; j < 4; j++) {
    const int col = bcolb + j * 16;
    const float bv = bias[col];
#pragma unroll
    for (int i = 0; i < 4; i++) {
#pragma unroll
      for (int r = 0; r < 4; r++) {
        const int row = browb + i * 16 + r;
        const float v = acc[i][j][r] + bv;
        if (OUT_BF16)
          ((unsigned short*)Cout)[(size_t)row * N + col] = f2bf(v);
        else
          ((float*)Cout)[(size_t)row * N + col] = v;
      }
    }
  }
}

// ---------------------------------------------------------------------------
// attn_mfma: one wave per (window b, head h); 4 waves/block, private LDS each.
// QK^T: 16 mfma_16x16x32_bf16 (K=32=hd, one step).  softmax w/o max-sub
// (|S|<~15 << 88 overflow bound).  Row sums via ones-column in Vt (extra
// n-tile in PV) -> no cross-lane reductions.  P: C-layout -> A-layout via LDS.
// ---------------------------------------------------------------------------
__global__ __launch_bounds__(256)
void attn_mfma(const unsigned short* __restrict__ qkv,
               const float* __restrict__ mask,
               const float* __restrict__ biasP,
               unsigned short* __restrict__ attn_out) {
  // per-wave region 16128 B: Vt[0,6912) 48 rows *144B; Q[6912,11008) 64*64B;
  // K[11008,15104) 64*64B; pad[15104,16128). P aliases [6912,16128): 64*144B.
  __shared__ __align__(16) char lds[4][16128];

  const int tid  = threadIdx.x;
  const int wave = tid >> 6;
  const int lane = tid & 63;
  const int lm   = lane & 15;
  const int q    = lane >> 4;

  const int pair = blockIdx.x * 4 + wave;
  const int b    = pair / HEADS;
  const int h    = pair - b * HEADS;
  const int g    = b & (NMASK - 1);

  char* Wl = lds[wave];
  char* Vt = Wl;
  char* Qb = Wl + 6912;
  char* Kb = Wl + 11008;
  char* Pb = Wl + 6912;

  const unsigned short* qbase = qkv + (size_t)b * NTOK * (3 * DIM) + h * HD;

  // ---- stage Q, K (zero-padded rows >= 49), row-major stride 64 B ----
  {
    const int row   = (tid & 63) >> 2;      // careful: use lane-based below
    (void)row;
  }
  const uint4 zero16 = {0u, 0u, 0u, 0u};
#pragma unroll
  for (int r = 0; r < 4; r++) {
    const int row   = r * 16 + (lane >> 2);
    const int chunk = lane & 3;
    uint4 vq = zero16, vk = zero16;
    if (row < NTOK) {
      vq = *(const uint4*)(qbase + (size_t)row * (3 * DIM) + chunk * 8);
      vk = *(const uint4*)(qbase + (size_t)row * (3 * DIM) + DIM + chunk * 8);
    }
    *(uint4*)(Qb + row * 64 + chunk * 16) = vq;
    *(uint4*)(Kb + row * 64 + chunk * 16) = vk;
  }
  // ---- stage V transposed: Vt[d][j], stride 144 B; cols j>=49 zeroed ----
  const unsigned short* vbase = qbase + 2 * DIM;
#pragma unroll 8
  for (int d = 0; d < HD; d++) {
    unsigned short v = 0;
    if (lane < NTOK) v = vbase[(size_t)lane * (3 * DIM) + d];
    *(unsigned short*)(Vt + d * 144 + lane * 2) = v;
  }
  // ones row (row-sum trick): Vt[32][j] = 1.0 for j<49 else 0
  *(unsigned short*)(Vt + HD * 144 + lane * 2) =
      (lane < NTOK) ? (unsigned short)0x3F80 : (unsigned short)0;

  // ---- Q/K fragments + QK^T MFMAs ----
  bf16x8 qf[4], kf[4];
#pragma unroll
  for (int i = 0; i < 4; i++) {
    qf[i] = *(const bf16x8*)(Qb + (i * 16 + lm) * 64 + q * 16);
    kf[i] = *(const bf16x8*)(Kb + (i * 16 + lm) * 64 + q * 16);
  }
  floatx4 S[4][4] = {};
#pragma unroll
  for (int i = 0; i < 4; i++)
#pragma unroll
    for (int j = 0; j < 4; j++)
      S[i][j] = __builtin_amdgcn_mfma_f32_16x16x32_bf16(qf[i], kf[j], S[i][j], 0, 0, 0);

  // ---- softmax (no max-sub) + write P (bf16) to LDS ----
  const float scale = 0.17677669529663687f;  // 32^-0.5
  const float*  bb  = biasP + (size_t)h * 4096;
  const float*  mb  = mask + (size_t)g * (NTOK * NTOK);
#pragma unroll
  for (int i = 0; i < 4; i++) {
#pragma unroll
    for (int j = 0; j < 4; j++) {
      const float4 bm4 = ((const float4*)bb)[(i * 4 + j) * 64 + lane];
      const float* bmp = (const float*)&bm4;
      const int cc = min(j * 16 + lm, NTOK - 1);
#pragma unroll
      for (int r = 0; r < 4; r++) {
        const int rr = min(i * 16 + q * 4 + r, NTOK - 1);
        const float mv = mb[rr * NTOK + cc];
        const float s  = fmaf(S[i][j][r], scale, bmp[r] + mv);
        const float p  = __expf(s);
        *(unsigned short*)(Pb + (i * 16 + q * 4 + r) * 144 + (j * 16 + lm) * 2) = f2bf(p);
      }
    }
  }

  // ---- PV MFMAs: M=64(i), N=48 (32 d + ones col), K=64(j), 2 k-steps ----
  floatx4 O[4][3] = {};
#pragma unroll
  for (int ks = 0; ks < 2; ks++) {
    bf16x8 pf[4], vf[3];
#pragma unroll
    for (int i = 0; i < 4; i++)
      pf[i] = *(const bf16x8*)(Pb + (i * 16 + lm) * 144 + ks * 64 + q * 16);
#pragma unroll
    for (int n = 0; n < 3; n++)
      vf[n] = *(const bf16x8*)(Vt + (n * 16 + lm) * 144 + ks * 64 + q * 16);
#pragma unroll
    for (int i = 0; i < 4; i++)
#pragma unroll
      for (int n = 0; n < 3; n++)
        O[i][n] = __builtin_amdgcn_mfma_f32_16x16x32_bf16(pf[i], vf[n], O[i][n], 0, 0, 0);
  }

  // ---- epilogue: divide by row sum (col 32, held in lm==0 lanes), store ----
  unsigned short* obase = attn_out + (size_t)b * NTOK * DIM + h * HD;
#pragma unroll
  for (int i = 0; i < 4; i++) {
#pragma unroll
    for (int r = 0; r < 4; r++) {
      const float sv  = __shfl(O[i][2][r], tid & 48, 64);
      const float inv = __builtin_amdgcn_rcpf(sv);
      const int row = i * 16 + q * 4 + r;
      if (row < NTOK) {
#pragma unroll
        for (int n = 0; n < 2; n++)
          obase[(size_t)row * DIM + n * 16 + lm] = f2bf(O[i][n][r] * inv);
      }
    }
  }
}

// ---------------------------------------------------------------------------
// launch
// ---------------------------------------------------------------------------
extern "C" void kernel_launch(void* const* d_in, const int* in_sizes, int n_in,
                              void* d_out, int out_size, void* d_ws, size_t ws_size,
                              hipStream_t stream) {
  const float* x         = (const float*)d_in[0];
  const float* mask      = (const float*)d_in[1];
  const float* qkv_w     = (const float*)d_in[2];
  const float* qkv_b     = (const float*)d_in[3];
  const float* proj_w    = (const float*)d_in[4];
  const float* proj_b    = (const float*)d_in[5];
  const float* rel_table = (const float*)d_in[6];
  const int*   rel_index = (const int*)d_in[7];
  float* out = (float*)d_out;

  char* ws = (char*)d_ws;
  unsigned short* xb      = (unsigned short*)(ws);                 // 77,070,336 B
  unsigned short* qkvbuf  = (unsigned short*)(ws + 77070336);      // 231,211,008 B
  unsigned short* qkv_wb  = (unsigned short*)(ws + 308281344);     // 884,736 B
  unsigned short* proj_wb = (unsigned short*)(ws + 309166080);     // 294,912 B
  float*          biasP   = (float*)(ws + 309460992);              // 196,608 B

  prep_kernel<<<2048, 256, 0, stream>>>(x, qkv_w, proj_w, rel_table, rel_index,
                                        xb, qkv_wb, proj_wb, biasP);

  gemm_bt<1><<<dim3((3 * DIM) / 128, MTOT / 128), 256, 0, stream>>>(
      xb, qkv_wb, qkv_b, qkvbuf, MTOT, 3 * DIM, DIM);

  attn_mfma<<<dim3(NWIN * HEADS / 4), 256, 0, stream>>>(qkvbuf, mask, biasP,
                                                        xb /*attn_out*/);

  gemm_bt<0><<<dim3(DIM / 128, MTOT / 128), 256, 0, stream>>>(
      xb /*attn_out*/, proj_wb, proj_b, out, MTOT, DIM, DIM);
}